// Round 1
// baseline (92.372 us; speedup 1.0000x reference)
//
#include <hip/hip_runtime.h>
#include <math.h>

// Channelatt: x(32,256,56,56) f32 -> x * sigmoid(gate(n,c))
// gate = LN(LN(x_g + x_s + x_l) @ tw_w.T + tw_b) -> sigmoid
// x_g: softmax-weighted spatial sum; x_s: wmax*max + wdct*DCT pool; x_l: conv1d over C.

#define N_ 32
#define C_ 256
#define H_ 56
#define W_ 56
#define S_ 3136   // H_*W_
#define LN_EPS 1e-5f

__device__ __forceinline__ float wave_sum(float v) {
  #pragma unroll
  for (int o = 32; o > 0; o >>= 1) v += __shfl_xor(v, o);
  return v;
}
__device__ __forceinline__ float wave_max(float v) {
  #pragma unroll
  for (int o = 32; o > 0; o >>= 1) v = fmaxf(v, __shfl_xor(v, o));
  return v;
}
// 256-thread (4-wave) block sum, broadcast to all threads. red = float[4] shared.
__device__ __forceinline__ float block_sum(float v, float* red) {
  int lane = threadIdx.x & 63, wid = threadIdx.x >> 6;
  float w = wave_sum(v);
  __syncthreads();               // protect red from previous use
  if (lane == 0) red[wid] = w;
  __syncthreads();
  return red[0] + red[1] + red[2] + red[3];
}

// K1: logits[n,s] = sum_c x[n,c,s] * gc_w[c]   (gc_b dropped: softmax shift-invariant)
__global__ void k_logits(const float* __restrict__ x, const float* __restrict__ gc_w,
                         float* __restrict__ logits) {
  __shared__ float gw[C_];
  int tid = threadIdx.x;
  gw[tid] = gc_w[tid];
  __syncthreads();
  int n = blockIdx.y;
  int s = blockIdx.x * 256 + tid;
  if (s >= S_) return;
  const float* xp = x + (size_t)n * C_ * S_ + s;
  float acc = 0.f;
  #pragma unroll 8
  for (int c = 0; c < C_; ++c) acc += xp[(size_t)c * S_] * gw[c];
  logits[n * S_ + s] = acc;
}

// K2: softmax over s per n. One block per n; 3136 values live in 13 regs/thread.
__global__ void k_softmax(const float* __restrict__ logits, float* __restrict__ attn) {
  int n = blockIdx.x, tid = threadIdx.x;
  __shared__ float red[4];
  float v[13];
  float m = -INFINITY;
  #pragma unroll
  for (int k = 0; k < 13; ++k) {
    int s = tid + k * 256;
    v[k] = (s < S_) ? logits[n * S_ + s] : -INFINITY;
    m = fmaxf(m, v[k]);
  }
  float wm = wave_max(m);
  int lane = tid & 63, wid = tid >> 6;
  if (lane == 0) red[wid] = wm;
  __syncthreads();
  m = fmaxf(fmaxf(red[0], red[1]), fmaxf(red[2], red[3]));
  float z = 0.f;
  #pragma unroll
  for (int k = 0; k < 13; ++k) { v[k] = expf(v[k] - m); z += v[k]; }  // exp(-inf)=0 for tail
  z = block_sum(z, red);
  float inv = 1.f / z;
  #pragma unroll
  for (int k = 0; k < 13; ++k) {
    int s = tid + k * 256;
    if (s < S_) attn[n * S_ + s] = v[k] * inv;
  }
}

// K3: per (n,c): x_g = sum_s x*attn, x_max = max_s x, x_dct = sum_s x*bh[h]*bw[w]
__global__ void k_stats(const float* __restrict__ x, const float* __restrict__ attn,
                        float* __restrict__ xg, float* __restrict__ xmax,
                        float* __restrict__ xdct) {
  int c = blockIdx.x, n = blockIdx.y;
  int tid = threadIdx.x;
  __shared__ float bh[H_], bw[W_];
  __shared__ float red[3][4];
  int grp = c >> 6;                 // 4 freq groups of 64 channels: (u,v) in {0,1}^2
  int u = grp >> 1, v = grp & 1;
  const float invs = 0.13363062f;   // 1/sqrt(56)
  const float sq2  = 1.41421356f;
  if (tid < H_) {
    float b = cosf((float)M_PI * u * (tid + 0.5f) / H_) * invs;
    bh[tid] = u ? b * sq2 : b;
  } else if (tid < H_ + W_) {
    int w = tid - H_;
    float b = cosf((float)M_PI * v * (w + 0.5f) / W_) * invs;
    bw[w] = v ? b * sq2 : b;
  }
  __syncthreads();
  const float* xp = x + ((size_t)n * C_ + c) * S_;
  const float* ap = attn + n * S_;
  float g = 0.f, mx = -INFINITY, d = 0.f;
  for (int s = tid; s < S_; s += 256) {
    float xv = xp[s];
    g += xv * ap[s];
    mx = fmaxf(mx, xv);
    int h = s / W_;
    d += xv * bh[h] * bw[s - h * W_];
  }
  float gs = wave_sum(g), ms = wave_max(mx), ds = wave_sum(d);
  int lane = tid & 63, wid = tid >> 6;
  if (lane == 0) { red[0][wid] = gs; red[1][wid] = ms; red[2][wid] = ds; }
  __syncthreads();
  if (tid == 0) {
    xg[n * C_ + c]   = red[0][0] + red[0][1] + red[0][2] + red[0][3];
    xmax[n * C_ + c] = fmaxf(fmaxf(red[1][0], red[1][1]), fmaxf(red[1][2], red[1][3]));
    xdct[n * C_ + c] = red[2][0] + red[2][1] + red[2][2] + red[2][3];
  }
}

// K4: all the small per-(n,c) math -> gate[n,c]. One block per n, thread = channel.
__global__ void k_gate(const float* __restrict__ xg, const float* __restrict__ xmax,
                       const float* __restrict__ xdct,
                       const float* __restrict__ lc_w, const float* __restrict__ lc_b,
                       const float* __restrict__ lcln_g, const float* __restrict__ lcln_b,
                       const float* __restrict__ tw_w, const float* __restrict__ tw_b,
                       const float* __restrict__ twln_g, const float* __restrict__ twln_b,
                       const float* __restrict__ wdct, const float* __restrict__ wmax,
                       float* __restrict__ gate) {
  int n = blockIdx.x, c = threadIdx.x;
  __shared__ float xs[C_ + 2];
  __shared__ float att_s[C_];
  __shared__ float red[4];
  float g  = xg[n * C_ + c];
  float sv = wmax[c] * xmax[n * C_ + c] + wdct[c] * xdct[n * C_ + c];
  xs[c + 1] = sv;
  if (c == 0) { xs[0] = 0.f; xs[C_ + 1] = 0.f; }
  __syncthreads();
  float xl = lc_w[0] * xs[c] + lc_w[1] * xs[c + 1] + lc_w[2] * xs[c + 2] + lc_b[0];
  float t = g + sv + xl;
  // LN over channels
  float mu  = block_sum(t, red) * (1.f / C_);
  float dv  = t - mu;
  float var = block_sum(dv * dv, red) * (1.f / C_);
  float att = dv * rsqrtf(var + LN_EPS) * lcln_g[c] + lcln_b[c];
  att_s[c] = att;
  __syncthreads();
  // att @ tw_w.T + tw_b : thread c reads its own row of tw_w (float4)
  float a2 = tw_b[c];
  const float4* wrow = (const float4*)(tw_w + c * C_);
  const float4* arow = (const float4*)att_s;
  #pragma unroll 8
  for (int k = 0; k < C_ / 4; ++k) {
    float4 wv = wrow[k], av = arow[k];
    a2 += wv.x * av.x + wv.y * av.y + wv.z * av.z + wv.w * av.w;
  }
  // LN + sigmoid
  float mu2  = block_sum(a2, red) * (1.f / C_);
  float d2   = a2 - mu2;
  float var2 = block_sum(d2 * d2, red) * (1.f / C_);
  float z = d2 * rsqrtf(var2 + LN_EPS) * twln_g[c] + twln_b[c];
  gate[n * C_ + c] = 1.f / (1.f + expf(-z));
}

// K5: out = x * gate[n,c], float4 grid-stride
__global__ void k_scale(const float* __restrict__ x, const float* __restrict__ gate,
                        float* __restrict__ out) {
  const float4* x4 = (const float4*)x;
  float4* o4 = (float4*)out;
  const int total = N_ * C_ * (S_ / 4);   // 6,422,528
  for (int i = blockIdx.x * blockDim.x + threadIdx.x; i < total;
       i += gridDim.x * blockDim.x) {
    int nc = i / (S_ / 4);
    float gv = gate[nc];
    float4 v = x4[i];
    v.x *= gv; v.y *= gv; v.z *= gv; v.w *= gv;
    o4[i] = v;
  }
}

extern "C" void kernel_launch(void* const* d_in, const int* in_sizes, int n_in,
                              void* d_out, int out_size, void* d_ws, size_t ws_size,
                              hipStream_t stream) {
  const float* x      = (const float*)d_in[0];
  const float* gc_w   = (const float*)d_in[1];
  // d_in[2] = gc_b: softmax shift-invariant, unused
  const float* lc_w   = (const float*)d_in[3];
  const float* lc_b   = (const float*)d_in[4];
  const float* lcln_g = (const float*)d_in[5];
  const float* lcln_b = (const float*)d_in[6];
  const float* tw_w   = (const float*)d_in[7];
  const float* tw_b   = (const float*)d_in[8];
  const float* twln_g = (const float*)d_in[9];
  const float* twln_b = (const float*)d_in[10];
  const float* wdct   = (const float*)d_in[11];
  const float* wmax   = (const float*)d_in[12];
  float* out = (float*)d_out;

  float* ws     = (float*)d_ws;
  float* logits = ws;                      // N*S
  float* attn   = ws + (size_t)N_ * S_;    // N*S
  float* xg     = ws + (size_t)2 * N_ * S_;// N*C
  float* xmax_  = xg + N_ * C_;            // N*C
  float* xdct_  = xmax_ + N_ * C_;         // N*C
  float* gate   = xdct_ + N_ * C_;         // N*C

  hipLaunchKernelGGL(k_logits, dim3((S_ + 255) / 256, N_), dim3(256), 0, stream,
                     x, gc_w, logits);
  hipLaunchKernelGGL(k_softmax, dim3(N_), dim3(256), 0, stream, logits, attn);
  hipLaunchKernelGGL(k_stats, dim3(C_, N_), dim3(256), 0, stream,
                     x, attn, xg, xmax_, xdct_);
  hipLaunchKernelGGL(k_gate, dim3(N_), dim3(256), 0, stream,
                     xg, xmax_, xdct_, lc_w, lc_b, lcln_g, lcln_b,
                     tw_w, tw_b, twln_g, twln_b, wdct, wmax, gate);
  hipLaunchKernelGGL(k_scale, dim3(2048), dim3(256), 0, stream, x, gate, out);
}